// Round 5
// baseline (3722.994 us; speedup 1.0000x reference)
//
#include <hip/hip_runtime.h>
#include <hip/hip_bf16.h>
#include <stdint.h>

#define M_DIM 4096
#define N_DIM 11008
#define K_DIM 4096

typedef float f32x4 __attribute__((ext_vector_type(4)));
typedef __bf16 bf16x8 __attribute__((ext_vector_type(8)));
typedef unsigned short u16x8 __attribute__((ext_vector_type(8)));
typedef unsigned short u16x4 __attribute__((ext_vector_type(4)));

typedef __attribute__((address_space(1))) const unsigned int guint;
typedef __attribute__((address_space(3))) unsigned int luint;
#define GLOAD_LDS16(g, l) \
    __builtin_amdgcn_global_load_lds((guint*)(g), (luint*)(l), 16, 0, 0)

#define WAIT_VM4() asm volatile("s_waitcnt vmcnt(4)" ::: "memory")
#define WAIT_VM0() asm volatile("s_waitcnt vmcnt(0)" ::: "memory")

__device__ __forceinline__ unsigned short f2bf(float f) {
    union { float f; unsigned u; } v; v.f = f;
    return (unsigned short)((v.u + 0x7FFFu + ((v.u >> 16) & 1u)) >> 16);
}

// ---------------- Pass 1a: X f32 -> bf16 ----------------
__global__ void __launch_bounds__(256) cvt_x_kernel(
    const float* __restrict__ X, __hip_bfloat16* __restrict__ Y)
{
    const size_t i = ((size_t)blockIdx.x * 256 + threadIdx.x) * 8;
    f32x4 a = *reinterpret_cast<const f32x4*>(X + i);
    f32x4 b = *reinterpret_cast<const f32x4*>(X + i + 4);
    bf16x8 h;
    #pragma unroll
    for (int e = 0; e < 4; ++e) { h[e] = (__bf16)a[e]; h[e + 4] = (__bf16)b[e]; }
    *reinterpret_cast<bf16x8*>(Y + i) = h;
}

// ---------------- Pass 1b: GPTQ int4 -> Wt[n][k] bf16 ----------------
__global__ void __launch_bounds__(256) dequant_kernel(
    const int* __restrict__ QW, const int* __restrict__ QZ,
    const float* __restrict__ SC, __hip_bfloat16* __restrict__ Wt)
{
    const int n   = blockIdx.x * 64 + (threadIdx.x & 63);
    const int k64 = blockIdx.y * 4 + (threadIdx.x >> 6);
    const int g   = k64 >> 1;
    const int zp  = ((unsigned)QZ[g * (N_DIM / 8) + (n >> 3)] >> ((n & 7) << 2)) & 15;
    const float sc = SC[g * N_DIM + n];
    const float zs = (float)zp * sc;
    #pragma unroll
    for (int r = 0; r < 8; ++r) {
        const unsigned qw = (unsigned)QW[(size_t)(k64 * 8 + r) * N_DIM + n];
        bf16x8 h;
        #pragma unroll
        for (int j = 0; j < 8; ++j)
            h[j] = (__bf16)((float)((qw >> (j * 4)) & 15u) * sc - zs);
        *reinterpret_cast<bf16x8*>(Wt + (size_t)n * K_DIM + k64 * 64 + r * 8) = h;
    }
}

// ---------------- Pass 2: 256x256 bf16 GEMM, 8 waves x (128x64) ----------------
// 512 threads, BK=32, 2-buffer LDS ring (2 x 32KB = 64KB -> 2 blocks/CU),
// counted vmcnt(4), 2 barriers/K-tile, XOR slot-swizzle via pre-swizzled
// global source (linear gload_lds dest).  LDS-read intensity 42.7 FLOP/B.
__global__ void __launch_bounds__(512, 4) gemm_bf16_kernel(
    const __hip_bfloat16* __restrict__ A,   // [4096][4096] (m,k)
    const __hip_bfloat16* __restrict__ Bt,  // [11008][4096] (n,k)
    const float* __restrict__ BIAS, float* __restrict__ OUT)
{
    // buf d at d*32768; within buf: A rows 0..255 at +0 (row*64B), B at +16384
    __shared__ __align__(16) unsigned char lds[65536];

    const int tid  = threadIdx.x;
    const int wave = tid >> 6;
    const int lane = tid & 63;
    const int l15  = lane & 15;
    const int lhi  = lane >> 4;
    const int wr   = wave >> 2;   // 0..1 (M, 128-row strips)
    const int wc   = wave & 3;    // 0..3 (N, 64-col strips)

    // XCD-bijective swizzle: 688 blocks = 8 XCDs x 86, M-fastest within chunk
    const int bid = blockIdx.x;
    const int swz = (bid & 7) * 86 + (bid >> 3);
    const int m0  = (swz & 15) * 256;
    const int n0  = (swz >> 4) * 256;

    // staging: thread t owns dest byte t*16 (+8192 for rows 128..255).
    // row = t>>2, slot = t&3; source k pre-swizzled: slot ^ ((row>>1)&3)
    const int r_loc = tid >> 2;                        // 0..127
    const int kswz8 = ((tid & 3) ^ ((tid >> 3) & 3)) * 8;
    const __hip_bfloat16* Asrc = A  + (size_t)(m0 + r_loc) * K_DIM + kswz8;
    const __hip_bfloat16* Bsrc = Bt + (size_t)(n0 + r_loc) * K_DIM + kswz8;
    const int ldst = wave * 1024;  // 64 lanes * 16B

    // fragment-read offsets (constant per thread; add buf base)
    const int slotx = ((lhi ^ ((l15 >> 1) & 3)) << 4);
    int aoff[8], boff[4];
    #pragma unroll
    for (int i = 0; i < 8; ++i)
        aoff[i] = (wr * 128 + i * 16 + l15) * 64 + slotx;
    #pragma unroll
    for (int j = 0; j < 4; ++j)
        boff[j] = 16384 + (wc * 64 + j * 16 + l15) * 64 + slotx;

    f32x4 acc[8][4] = {};

    auto stage = [&](int c) {
        const int buf = (c & 1) * 32768;
        const size_t kof = (size_t)c * 32;
        GLOAD_LDS16(Asrc + kof,                        lds + buf + ldst);
        GLOAD_LDS16(Asrc + kof + (size_t)128 * K_DIM,  lds + buf + 8192 + ldst);
        GLOAD_LDS16(Bsrc + kof,                        lds + buf + 16384 + ldst);
        GLOAD_LDS16(Bsrc + kof + (size_t)128 * K_DIM,  lds + buf + 16384 + 8192 + ldst);
    };

    auto compute = [&](int buf) {
        bf16x8 afr[4], bfr[4];
        #pragma unroll
        for (int j = 0; j < 4; ++j)
            bfr[j] = *reinterpret_cast<const bf16x8*>(lds + buf + boff[j]);
        #pragma unroll
        for (int i = 0; i < 4; ++i)
            afr[i] = *reinterpret_cast<const bf16x8*>(lds + buf + aoff[i]);
        __builtin_amdgcn_s_setprio(1);
        #pragma unroll
        for (int i = 0; i < 4; ++i)
            #pragma unroll
            for (int j = 0; j < 4; ++j)
                acc[i][j] = __builtin_amdgcn_mfma_f32_16x16x32_bf16(
                    afr[i], bfr[j], acc[i][j], 0, 0, 0);
        __builtin_amdgcn_s_setprio(0);
        #pragma unroll
        for (int i = 0; i < 4; ++i)
            afr[i] = *reinterpret_cast<const bf16x8*>(lds + buf + aoff[i + 4]);
        __builtin_amdgcn_s_setprio(1);
        #pragma unroll
        for (int i = 0; i < 4; ++i)
            #pragma unroll
            for (int j = 0; j < 4; ++j)
                acc[i + 4][j] = __builtin_amdgcn_mfma_f32_16x16x32_bf16(
                    afr[i], bfr[j], acc[i + 4][j], 0, 0, 0);
        __builtin_amdgcn_s_setprio(0);
    };

    stage(0); stage(1);   // 8 loads in flight

    for (int c = 0; c < 126; ++c) {
        WAIT_VM4();                          // own-wave stage(c) done
        __builtin_amdgcn_s_barrier();        // all waves' stage(c) done
        __builtin_amdgcn_sched_barrier(0);
        compute((c & 1) * 32768);
        __builtin_amdgcn_s_barrier();        // all waves finished reading buf
        __builtin_amdgcn_sched_barrier(0);
        stage(c + 2);                        // overwrite just-freed buffer
    }
    WAIT_VM4();                              // c = 126
    __builtin_amdgcn_s_barrier();
    __builtin_amdgcn_sched_barrier(0);
    compute(0);
    WAIT_VM0();                              // c = 127
    __builtin_amdgcn_s_barrier();
    __builtin_amdgcn_sched_barrier(0);
    compute(32768);

    // epilogue: OUT = acc + bias
    #pragma unroll
    for (int j = 0; j < 4; ++j) {
        const int n    = n0 + wc * 64 + j * 16 + l15;
        const float bv = BIAS[n];
        #pragma unroll
        for (int i = 0; i < 8; ++i) {
            const int mb = m0 + wr * 128 + i * 16 + (lhi << 2);
            #pragma unroll
            for (int t = 0; t < 4; ++t)
                OUT[(size_t)(mb + t) * N_DIM + n] = acc[i][j][t] + bv;
        }
    }
}

// ---------------- Fallback: round-1 fused kernel ----------------
__global__ void __launch_bounds__(256) gptq_gemm_kernel(
    const float* __restrict__ X, const int* __restrict__ QW,
    const int* __restrict__ QZ, const float* __restrict__ SC,
    const float* __restrict__ BIAS, float* __restrict__ OUT)
{
    __shared__ __align__(16) unsigned char slds[32768];
    const int tid  = threadIdx.x;
    const int n0   = blockIdx.x * 128;
    const int m0   = blockIdx.y * 128;
    const int wave = tid >> 6;
    const int lane = tid & 63;
    const int wm   = (wave >> 1) * 64;
    const int wn   = (wave & 1) * 64;
    const int l15  = lane & 15;
    const int lhi  = lane >> 4;
    const int arow  = tid >> 4;
    const int acol4 = (tid & 15) << 2;
    const int bnl   = tid & 127;
    const int brb   = tid >> 7;
    const int col   = n0 + bnl;

    f32x4 acc[4][4] = {};
    for (int kt = 0; kt < K_DIM / 64; ++kt) {
        const int k0 = kt * 64;
        #pragma unroll
        for (int r8 = 0; r8 < 8; ++r8) {
            const int row = (r8 << 4) + arow;
            f32x4 v = *reinterpret_cast<const f32x4*>(
                X + (size_t)(m0 + row) * K_DIM + (k0 + acol4));
            u16x4 h;
            #pragma unroll
            for (int e = 0; e < 4; ++e) h[e] = f2bf(v[e]);
            const int bo = row * 128 + ((acol4 << 1) ^ ((row & 7) << 4));
            *reinterpret_cast<u16x4*>(slds + bo) = h;
        }
        {
            const int g    = k0 >> 7;
            const int zp   = (((unsigned)QZ[g * (N_DIM / 8) + (col >> 3)])
                              >> ((col & 7) << 2)) & 15;
            const float sc = SC[g * N_DIM + col];
            const float zs = (float)zp * sc;
            #pragma unroll
            for (int rb = 0; rb < 4; ++rb) {
                const int rl = (rb << 1) + brb;
                const unsigned qw =
                    (unsigned)QW[(size_t)((k0 >> 3) + rl) * N_DIM + col];
                u16x8 h;
                #pragma unroll
                for (int j = 0; j < 8; ++j) {
                    float w = (float)((qw >> (j << 2)) & 15u) * sc - zs;
                    h[j] = f2bf(w);
                }
                const int bo = 16384 + bnl * 128 + ((rl << 4) ^ ((bnl & 7) << 4));
                *reinterpret_cast<u16x8*>(slds + bo) = h;
            }
        }
        __syncthreads();
        #pragma unroll
        for (int kk = 0; kk < 2; ++kk) {
            bf16x8 afr[4], bfr[4];
            #pragma unroll
            for (int i = 0; i < 4; ++i) {
                const int row = wm + (i << 4) + l15;
                afr[i] = *reinterpret_cast<const bf16x8*>(
                    slds + row * 128 + (((kk << 6) + (lhi << 4)) ^ ((row & 7) << 4)));
            }
            #pragma unroll
            for (int j = 0; j < 4; ++j) {
                const int n = wn + (j << 4) + l15;
                bfr[j] = *reinterpret_cast<const bf16x8*>(
                    slds + 16384 + n * 128 + (((kk << 6) + (lhi << 4)) ^ ((n & 7) << 4)));
            }
            #pragma unroll
            for (int i = 0; i < 4; ++i)
                #pragma unroll
                for (int j = 0; j < 4; ++j)
                    acc[i][j] = __builtin_amdgcn_mfma_f32_16x16x32_bf16(
                        afr[i], bfr[j], acc[i][j], 0, 0, 0);
        }
        __syncthreads();
    }
    #pragma unroll
    for (int j = 0; j < 4; ++j) {
        const int n    = n0 + wn + (j << 4) + l15;
        const float bv = BIAS[n];
        #pragma unroll
        for (int i = 0; i < 4; ++i) {
            const int mb = m0 + wm + (i << 4) + (lhi << 2);
            #pragma unroll
            for (int t = 0; t < 4; ++t)
                OUT[(size_t)(mb + t) * N_DIM + n] = acc[i][j][t] + bv;
        }
    }
}

extern "C" void kernel_launch(void* const* d_in, const int* in_sizes, int n_in,
                              void* d_out, int out_size, void* d_ws, size_t ws_size,
                              hipStream_t stream) {
    const float* X  = (const float*)d_in[0];
    const int*   QW = (const int*)d_in[1];
    const int*   QZ = (const int*)d_in[2];
    const float* SC = (const float*)d_in[3];
    const float* BI = (const float*)d_in[4];
    float*      OUT = (float*)d_out;

    const size_t xbf_bytes = (size_t)M_DIM * K_DIM * 2;
    const size_t wt_bytes  = (size_t)N_DIM * K_DIM * 2;

    if (ws_size >= xbf_bytes + wt_bytes) {
        __hip_bfloat16* Xbf = (__hip_bfloat16*)d_ws;
        __hip_bfloat16* Wt  = (__hip_bfloat16*)((char*)d_ws + xbf_bytes);

        cvt_x_kernel<<<(M_DIM * K_DIM) / (256 * 8), 256, 0, stream>>>(X, Xbf);
        dequant_kernel<<<dim3(N_DIM / 64, K_DIM / 256), 256, 0, stream>>>(QW, QZ, SC, Wt);
        gemm_bf16_kernel<<<dim3((M_DIM / 256) * (N_DIM / 256)), 512, 0, stream>>>(
            Xbf, Wt, BI, OUT);
    } else {
        gptq_gemm_kernel<<<dim3(N_DIM / 128, M_DIM / 128), 256, 0, stream>>>(
            X, QW, QZ, SC, BI, OUT);
    }
}

// Round 6
// 414.145 us; speedup vs baseline: 8.9896x; 8.9896x over previous
//
#include <hip/hip_runtime.h>
#include <hip/hip_bf16.h>
#include <stdint.h>

#define M_DIM 4096
#define N_DIM 11008
#define K_DIM 4096

typedef float f32x4 __attribute__((ext_vector_type(4)));
typedef __bf16 bf16x8 __attribute__((ext_vector_type(8)));
typedef unsigned short u16x8 __attribute__((ext_vector_type(8)));
typedef unsigned short u16x4 __attribute__((ext_vector_type(4)));

typedef __attribute__((address_space(1))) const unsigned int guint;
typedef __attribute__((address_space(3))) unsigned int luint;
#define GLOAD_LDS16(g, l) \
    __builtin_amdgcn_global_load_lds((guint*)(g), (luint*)(l), 16, 0, 0)

#define WAIT_VM8() asm volatile("s_waitcnt vmcnt(8)" ::: "memory")
#define WAIT_VM4() asm volatile("s_waitcnt vmcnt(4)" ::: "memory")
#define WAIT_VM0() asm volatile("s_waitcnt vmcnt(0)" ::: "memory")

__device__ __forceinline__ unsigned short f2bf(float f) {
    union { float f; unsigned u; } v; v.f = f;
    return (unsigned short)((v.u + 0x7FFFu + ((v.u >> 16) & 1u)) >> 16);
}

// ---------------- Pass 1a: X f32 -> bf16 ----------------
__global__ void __launch_bounds__(256) cvt_x_kernel(
    const float* __restrict__ X, __hip_bfloat16* __restrict__ Y)
{
    const size_t i = ((size_t)blockIdx.x * 256 + threadIdx.x) * 8;
    f32x4 a = *reinterpret_cast<const f32x4*>(X + i);
    f32x4 b = *reinterpret_cast<const f32x4*>(X + i + 4);
    bf16x8 h;
    #pragma unroll
    for (int e = 0; e < 4; ++e) { h[e] = (__bf16)a[e]; h[e + 4] = (__bf16)b[e]; }
    *reinterpret_cast<bf16x8*>(Y + i) = h;
}

// ---------------- Pass 1b: GPTQ int4 -> Wt[n][k] bf16 ----------------
__global__ void __launch_bounds__(256) dequant_kernel(
    const int* __restrict__ QW, const int* __restrict__ QZ,
    const float* __restrict__ SC, __hip_bfloat16* __restrict__ Wt)
{
    const int n   = blockIdx.x * 64 + (threadIdx.x & 63);
    const int k64 = blockIdx.y * 4 + (threadIdx.x >> 6);
    const int g   = k64 >> 1;
    const int zp  = ((unsigned)QZ[g * (N_DIM / 8) + (n >> 3)] >> ((n & 7) << 2)) & 15;
    const float sc = SC[g * N_DIM + n];
    const float zs = (float)zp * sc;
    #pragma unroll
    for (int r = 0; r < 8; ++r) {
        const unsigned qw = (unsigned)QW[(size_t)(k64 * 8 + r) * N_DIM + n];
        bf16x8 h;
        #pragma unroll
        for (int j = 0; j < 8; ++j)
            h[j] = (__bf16)((float)((qw >> (j * 4)) & 15u) * sc - zs);
        *reinterpret_cast<bf16x8*>(Wt + (size_t)n * K_DIM + k64 * 64 + r * 8) = h;
    }
}

// ---------------- Pass 2: 256x256 bf16 GEMM, 8 waves x (128x64) ----------------
// Round-3 skeleton (proven): 512 thr, BK=32, 4-buffer ring (128KB), counted
// vmcnt(8), zero-conflict slot-XOR swizzle, launch_bounds(512,2) -- NOTE:
// (512,4) caps regs at 128 and spills the 128-reg accumulator (round-5: 9GB
// scratch traffic, MfmaUtil 4%). Keep min-waves-per-EU = 2.
// NEW vs round 3: each K-tile split into 2 barrier-separated phases
// (T3 interleave): P0 = {bfr+afr[0..3] reads, A-stage(c+3), 16 MFMA},
// P1 = {afr[4..7] reads, B-stage(c+3), 16 MFMA}. B-frags live across barrier.
__global__ void __launch_bounds__(512, 2) gemm_bf16_kernel(
    const __hip_bfloat16* __restrict__ A,   // [4096][4096] (m,k)
    const __hip_bfloat16* __restrict__ Bt,  // [11008][4096] (n,k)
    const float* __restrict__ BIAS, float* __restrict__ OUT)
{
    extern __shared__ unsigned char lds[];  // 131072: buf d at d*32768; A +0, B +16384

    const int tid  = threadIdx.x;
    const int wave = tid >> 6;
    const int lane = tid & 63;
    const int l15  = lane & 15;
    const int lhi  = lane >> 4;
    const int wr   = wave >> 2;   // 0..1 (M, 128-row strips)
    const int wc   = wave & 3;    // 0..3 (N, 64-col strips)

    // XCD-bijective swizzle: 688 blocks = 8 XCDs x 86, M-fastest within chunk
    const int bid = blockIdx.x;
    const int swz = (bid & 7) * 86 + (bid >> 3);
    const int m0  = (swz & 15) * 256;
    const int n0  = (swz >> 4) * 256;

    // staging: thread t owns dest byte t*16 (+8192 for rows 128..255).
    // row = t>>2, slot = t&3; source k pre-swizzled: slot ^ ((row>>1)&3)
    const int r_loc = tid >> 2;                        // 0..127
    const int kswz8 = ((lane & 3) ^ ((lane >> 3) & 3)) * 8;
    const __hip_bfloat16* Asrc = A  + (size_t)(m0 + r_loc) * K_DIM + kswz8;
    const __hip_bfloat16* Bsrc = Bt + (size_t)(n0 + r_loc) * K_DIM + kswz8;
    const int ldst = wave * 1024;  // 64 lanes * 16B

    // fragment-read offsets (constant per thread; add buf base)
    const int slotx = ((lhi ^ ((l15 >> 1) & 3)) << 4);
    int aoff[8], boff[4];
    #pragma unroll
    for (int i = 0; i < 8; ++i)
        aoff[i] = (wr * 128 + i * 16 + l15) * 64 + slotx;
    #pragma unroll
    for (int j = 0; j < 4; ++j)
        boff[j] = 16384 + (wc * 64 + j * 16 + l15) * 64 + slotx;

    f32x4 acc[8][4] = {};

    auto stageA = [&](int c) {
        const int buf = (c & 3) * 32768;
        const size_t kof = (size_t)c * 32;
        GLOAD_LDS16(Asrc + kof,                        lds + buf + ldst);
        GLOAD_LDS16(Asrc + kof + (size_t)128 * K_DIM,  lds + buf + 8192 + ldst);
    };
    auto stageB = [&](int c) {
        const int buf = (c & 3) * 32768;
        const size_t kof = (size_t)c * 32;
        GLOAD_LDS16(Bsrc + kof,                        lds + buf + 16384 + ldst);
        GLOAD_LDS16(Bsrc + kof + (size_t)128 * K_DIM,  lds + buf + 16384 + 8192 + ldst);
    };

    // one K-tile: 2 phases, barrier-separated
    auto tile = [&](int c, bool st) {
        const int buf = (c & 3) * 32768;
        bf16x8 bfr[4], afr[4];
        // ---- phase 0 ----
        #pragma unroll
        for (int j = 0; j < 4; ++j)
            bfr[j] = *reinterpret_cast<const bf16x8*>(lds + buf + boff[j]);
        #pragma unroll
        for (int i = 0; i < 4; ++i)
            afr[i] = *reinterpret_cast<const bf16x8*>(lds + buf + aoff[i]);
        if (st) stageA(c + 3);
        __builtin_amdgcn_s_setprio(1);
        #pragma unroll
        for (int i = 0; i < 4; ++i)
            #pragma unroll
            for (int j = 0; j < 4; ++j)
                acc[i][j] = __builtin_amdgcn_mfma_f32_16x16x32_bf16(
                    afr[i], bfr[j], acc[i][j], 0, 0, 0);
        __builtin_amdgcn_s_setprio(0);
        __builtin_amdgcn_s_barrier();
        __builtin_amdgcn_sched_barrier(0);
        // ---- phase 1 ----
        #pragma unroll
        for (int i = 0; i < 4; ++i)
            afr[i] = *reinterpret_cast<const bf16x8*>(lds + buf + aoff[i + 4]);
        if (st) stageB(c + 3);
        __builtin_amdgcn_s_setprio(1);
        #pragma unroll
        for (int i = 0; i < 4; ++i)
            #pragma unroll
            for (int j = 0; j < 4; ++j)
                acc[i + 4][j] = __builtin_amdgcn_mfma_f32_16x16x32_bf16(
                    afr[i], bfr[j], acc[i + 4][j], 0, 0, 0);
        __builtin_amdgcn_s_setprio(0);
    };

    // prologue: fill 3 ring slots (12 loads in flight)
    stageA(0); stageB(0);
    stageA(1); stageB(1);
    stageA(2); stageB(2);

    for (int c = 0; c < 125; ++c) {
        WAIT_VM8();                          // tile c's 4 loads complete (own wave)
        __builtin_amdgcn_s_barrier();        // all waves' stage(c) complete
        __builtin_amdgcn_sched_barrier(0);
        tile(c, true);
    }
    WAIT_VM8();                              // c = 125 (126,127 in flight)
    __builtin_amdgcn_s_barrier();
    __builtin_amdgcn_sched_barrier(0);
    tile(125, false);
    WAIT_VM4();                              // c = 126
    __builtin_amdgcn_s_barrier();
    __builtin_amdgcn_sched_barrier(0);
    tile(126, false);
    WAIT_VM0();                              // c = 127
    __builtin_amdgcn_s_barrier();
    __builtin_amdgcn_sched_barrier(0);
    tile(127, false);

    // epilogue: OUT = acc + bias
    #pragma unroll
    for (int j = 0; j < 4; ++j) {
        const int n    = n0 + wc * 64 + j * 16 + l15;
        const float bv = BIAS[n];
        #pragma unroll
        for (int i = 0; i < 8; ++i) {
            const int mb = m0 + wr * 128 + i * 16 + (lhi << 2);
            #pragma unroll
            for (int t = 0; t < 4; ++t)
                OUT[(size_t)(mb + t) * N_DIM + n] = acc[i][j][t] + bv;
        }
    }
}

// ---------------- Fallback: round-1 fused kernel ----------------
__global__ void __launch_bounds__(256) gptq_gemm_kernel(
    const float* __restrict__ X, const int* __restrict__ QW,
    const int* __restrict__ QZ, const float* __restrict__ SC,
    const float* __restrict__ BIAS, float* __restrict__ OUT)
{
    __shared__ __align__(16) unsigned char slds[32768];
    const int tid  = threadIdx.x;
    const int n0   = blockIdx.x * 128;
    const int m0   = blockIdx.y * 128;
    const int wave = tid >> 6;
    const int lane = tid & 63;
    const int wm   = (wave >> 1) * 64;
    const int wn   = (wave & 1) * 64;
    const int l15  = lane & 15;
    const int lhi  = lane >> 4;
    const int arow  = tid >> 4;
    const int acol4 = (tid & 15) << 2;
    const int bnl   = tid & 127;
    const int brb   = tid >> 7;
    const int col   = n0 + bnl;

    f32x4 acc[4][4] = {};
    for (int kt = 0; kt < K_DIM / 64; ++kt) {
        const int k0 = kt * 64;
        #pragma unroll
        for (int r8 = 0; r8 < 8; ++r8) {
            const int row = (r8 << 4) + arow;
            f32x4 v = *reinterpret_cast<const f32x4*>(
                X + (size_t)(m0 + row) * K_DIM + (k0 + acol4));
            u16x4 h;
            #pragma unroll
            for (int e = 0; e < 4; ++e) h[e] = f2bf(v[e]);
            const int bo = row * 128 + ((acol4 << 1) ^ ((row & 7) << 4));
            *reinterpret_cast<u16x4*>(slds + bo) = h;
        }
        {
            const int g    = k0 >> 7;
            const int zp   = (((unsigned)QZ[g * (N_DIM / 8) + (col >> 3)])
                              >> ((col & 7) << 2)) & 15;
            const float sc = SC[g * N_DIM + col];
            const float zs = (float)zp * sc;
            #pragma unroll
            for (int rb = 0; rb < 4; ++rb) {
                const int rl = (rb << 1) + brb;
                const unsigned qw =
                    (unsigned)QW[(size_t)((k0 >> 3) + rl) * N_DIM + col];
                u16x8 h;
                #pragma unroll
                for (int j = 0; j < 8; ++j) {
                    float w = (float)((qw >> (j << 2)) & 15u) * sc - zs;
                    h[j] = f2bf(w);
                }
                const int bo = 16384 + bnl * 128 + ((rl << 4) ^ ((bnl & 7) << 4));
                *reinterpret_cast<u16x8*>(slds + bo) = h;
            }
        }
        __syncthreads();
        #pragma unroll
        for (int kk = 0; kk < 2; ++kk) {
            bf16x8 afr[4], bfr[4];
            #pragma unroll
            for (int i = 0; i < 4; ++i) {
                const int row = wm + (i << 4) + l15;
                afr[i] = *reinterpret_cast<const bf16x8*>(
                    slds + row * 128 + (((kk << 6) + (lhi << 4)) ^ ((row & 7) << 4)));
            }
            #pragma unroll
            for (int j = 0; j < 4; ++j) {
                const int n = wn + (j << 4) + l15;
                bfr[j] = *reinterpret_cast<const bf16x8*>(
                    slds + 16384 + n * 128 + (((kk << 6) + (lhi << 4)) ^ ((n & 7) << 4)));
            }
            #pragma unroll
            for (int i = 0; i < 4; ++i)
                #pragma unroll
                for (int j = 0; j < 4; ++j)
                    acc[i][j] = __builtin_amdgcn_mfma_f32_16x16x32_bf16(
                        afr[i], bfr[j], acc[i][j], 0, 0, 0);
        }
        __syncthreads();
    }
    #pragma unroll
    for (int j = 0; j < 4; ++j) {
        const int n    = n0 + wn + (j << 4) + l15;
        const float bv = BIAS[n];
        #pragma unroll
        for (int i = 0; i < 4; ++i) {
            const int mb = m0 + wm + (i << 4) + (lhi << 2);
            #pragma unroll
            for (int t = 0; t < 4; ++t)
                OUT[(size_t)(mb + t) * N_DIM + n] = acc[i][j][t] + bv;
        }
    }
}

extern "C" void kernel_launch(void* const* d_in, const int* in_sizes, int n_in,
                              void* d_out, int out_size, void* d_ws, size_t ws_size,
                              hipStream_t stream) {
    const float* X  = (const float*)d_in[0];
    const int*   QW = (const int*)d_in[1];
    const int*   QZ = (const int*)d_in[2];
    const float* SC = (const float*)d_in[3];
    const float* BI = (const float*)d_in[4];
    float*      OUT = (float*)d_out;

    const size_t xbf_bytes = (size_t)M_DIM * K_DIM * 2;
    const size_t wt_bytes  = (size_t)N_DIM * K_DIM * 2;

    if (ws_size >= xbf_bytes + wt_bytes) {
        __hip_bfloat16* Xbf = (__hip_bfloat16*)d_ws;
        __hip_bfloat16* Wt  = (__hip_bfloat16*)((char*)d_ws + xbf_bytes);

        cvt_x_kernel<<<(M_DIM * K_DIM) / (256 * 8), 256, 0, stream>>>(X, Xbf);
        dequant_kernel<<<dim3(N_DIM / 64, K_DIM / 256), 256, 0, stream>>>(QW, QZ, SC, Wt);
        gemm_bf16_kernel<<<dim3((M_DIM / 256) * (N_DIM / 256)), 512, 131072, stream>>>(
            Xbf, Wt, BI, OUT);
    } else {
        gptq_gemm_kernel<<<dim3(N_DIM / 128, M_DIM / 128), 256, 0, stream>>>(
            X, QW, QZ, SC, BI, OUT);
    }
}